// Round 5
// baseline (573.222 us; speedup 1.0000x reference)
//
#include <hip/hip_runtime.h>

#define NB   4096
#define NIN  1024
#define NH   2048
#define NOUT 1024
#define NH4  8192   // 4*NH

typedef short short8 __attribute__((ext_vector_type(8)));
typedef float f32x4 __attribute__((ext_vector_type(4)));
typedef float f32x16 __attribute__((ext_vector_type(16)));
typedef unsigned short ushort8v __attribute__((ext_vector_type(8)));

__device__ __forceinline__ float bf2f(unsigned short u) {
  union { unsigned int i; float f; } c; c.i = ((unsigned int)u) << 16; return c.f;
}
__device__ __forceinline__ unsigned short f2bf(float f) {
  union { float f; unsigned int i; } c; c.f = f;
  unsigned int u = c.i;
  u += 0x7FFFu + ((u >> 16) & 1u);   // RNE; inputs are finite
  return (unsigned short)(u >> 16);
}
__device__ __forceinline__ float sigf(float x) { return 1.0f / (1.0f + __expf(-x)); }
__device__ __forceinline__ float tanh_f(float x) { return 1.0f - 2.0f / (__expf(2.0f * x) + 1.0f); }

// ---------------- workspace layout (ushort elems), compile-time ----------------
#define CNT_INP  ((size_t)NB * NIN)
#define CNT_H0   ((size_t)NB * NH)
#define CNT_WXG  ((size_t)NH * NIN)
#define CNT_WHG  ((size_t)NH * NH)
#define CNT_WD   ((size_t)NOUT * NH)
#define OFF_XB   ((size_t)0)
#define OFF_H0B  (OFF_XB + CNT_INP)
#define OFF_HXB  (OFF_H0B + CNT_H0)
#define OFF_WX   (OFF_HXB + CNT_H0)
#define OFF_WH   (OFF_WX + 4 * CNT_WXG)
#define OFF_WD   (OFF_WH + 4 * CNT_WHG)
#define OFF_ZX   (OFF_WD + CNT_WD)
#define OFF_ZH   (OFF_ZX + (size_t)NB * NH4)
#define CVT_TOTAL (OFF_WD + CNT_WD)

// ---------------- single fused fp32->bf16 convert over all 11 segments ----------------
struct CvtArgs { const float* src[11]; };

__global__ __launch_bounds__(256) void cvt_all(CvtArgs a, unsigned short* __restrict__ dstBase) {
  const size_t i = ((size_t)blockIdx.x * 256 + threadIdx.x) * 8;
  if (i >= CVT_TOTAL) return;
  const size_t cnt[11] = {CNT_INP, CNT_H0, CNT_WXG, CNT_WXG, CNT_WXG, CNT_WXG,
                          CNT_WHG, CNT_WHG, CNT_WHG, CNT_WHG, CNT_WD};
  const size_t dst[11] = {OFF_XB, OFF_H0B,
                          OFF_WX, OFF_WX + CNT_WXG, OFF_WX + 2 * CNT_WXG, OFF_WX + 3 * CNT_WXG,
                          OFF_WH, OFF_WH + CNT_WHG, OFF_WH + 2 * CNT_WHG, OFF_WH + 3 * CNT_WHG,
                          OFF_WD};
  size_t base = 0;
#pragma unroll
  for (int s = 0; s < 11; s++) {
    if (i < base + cnt[s]) {
      const size_t off = i - base;
      const float* sp = a.src[s] + off;
      float4 v0 = *(const float4*)(sp);
      float4 v1 = *(const float4*)(sp + 4);
      ushort8v o;
      o[0] = f2bf(v0.x); o[1] = f2bf(v0.y); o[2] = f2bf(v0.z); o[3] = f2bf(v0.w);
      o[4] = f2bf(v1.x); o[5] = f2bf(v1.y); o[6] = f2bf(v1.z); o[7] = f2bf(v1.w);
      *(ushort8v*)(dstBase + dst[s] + off) = o;
      return;
    }
    base += cnt[s];
  }
}

// ---------------- async global->LDS, 16B/lane ----------------
__device__ __forceinline__ void gload16(const void* g, void* l) {
  __builtin_amdgcn_global_load_lds((const __attribute__((address_space(1))) void*)g,
                                   (__attribute__((address_space(3))) void*)l, 16, 0, 0);
}

#define SCH0  __builtin_amdgcn_sched_barrier(0)
#define BARR  __builtin_amdgcn_s_barrier()
#define LGKM0 asm volatile("s_waitcnt lgkmcnt(0)" ::: "memory")
#define VMC6  asm volatile("s_waitcnt vmcnt(6)" ::: "memory")
#define VMC0  asm volatile("s_waitcnt vmcnt(0)" ::: "memory")
#define PRIO1 __builtin_amdgcn_s_setprio(1)
#define PRIO0 __builtin_amdgcn_s_setprio(0)
#define MFMA32(A, B, C) __builtin_amdgcn_mfma_f32_32x32x16_bf16((A), (B), (C), 0, 0, 0)

#define SWZ(R) (((R) & 7) ^ ((((R) >> 3) & 3) << 1))

// ======================================================================
// R4->R5: 32x32x16 MFMA + early-publish 2-barrier rotation.
// NT layout: C[m][n] = sum_k A[m,k]*B[n,k]. 512 thr = 8 waves (2M x 4N);
// per-wave 128x64; BK=64; LDS 128 KiB double-buffered.
//
// R4 diagnosis (counters, 5250 cyc/tile): MFMA 2483 + LDS 2304 + overhead in
// SERIES. q10/q11 (1241 cyc MFMA) had zero LDS work while next tile's reads
// sat blocked behind the end-of-tile publish. Fix:
//  (a) 32x32x16 MFMA: floor 2483->2066 cyc (m119: 2495 vs 2176 TF), 32 MFMA
//      + 24 ds_read per wave-tile (instr count halved).
//  (b) single BARR#1 after c3 (ALL fragments of tile t in regs -> stage
//      B0,B1,A0(t+2) into cur buffers), VMC6, BARR#2 publishes t+1, THEN c4
//      (pure-reg) -> next tile's 24 reads stream under c4+c1..c3(t+1).
//      Steady state max(LDS 2304, MFMA 2066) instead of sum.
//
// Per-tile schedule (clusters of 8 MFMA32):
//   reads b0(4)+a01(8); stage A1(t+1)->As[nxt]; reads b1(4); reads a23(8)
//   c1 (mt01 x jt0)  [lgkm waits first 12, counted]
//   c2 (mt01 x jt1)  [16]
//   c3 (mt23 x jt0)  [24]
//   BARR#1; stage B0,B1(t+2)->Bs[cur], A0(t+2)->As[cur]; VMC6; BARR#2
//   c4 (mt23 x jt1)  [pure reg, overlaps next tile's reads]
// vmcnt ledger: entry 6 (t+1.B0B1A0) +2(A1 t+1) +6(t+2) = 14; vmcnt(6)
// drains 8 oldest = all of t+1; BARR#2 publishes. Race proofs: staged regions'
// last readers moved data to regs before BARR#1 (A reads in groups 1/3, B in
// 1/2, all pre-BARR#1); A1(t+1)->other buf last read before t-1's BARR#1.
// Tail: clamped t1/t2 stages rewrite already-consumed regions (benign, counts
// exact); VMC0+BARR before epilogue reuses LDS.
//
// Swizzle (R2-verified, 0 conflicts): chunk c of row r at slot c^SWZ(r);
// staging pre-swizzles global chunk ck = slot^rloc^((wid&3)<<1). 32-row reads:
// unit {l,l+8,l+16,l+24} -> slots c^{0,2,4,6}, 4 distinct.
// Fragment/C layouts taken verbatim from the verified 32x32 kernel:
// A/B: m(n)=lane&31, k-chunk=ks*2+(lane>>5); C/D: col=lane&31,
// row=(reg&3)+8*(reg>>2)+4*(lane>>5).
// Epilogue (R2-verified WRITE_SIZE=ideal): per-wave 32x68 LDS buffer,
// readback b128, 128B fully-covered global segments.
// ======================================================================

__device__ __forceinline__ void stage_half(const unsigned short* __restrict__ G, size_t thrOff, int K,
                                           int R0, int H, int T, unsigned short* __restrict__ ldbase, int wid) {
  const unsigned short* gs = G + thrOff + (size_t)(R0 + H * 128) * K + (size_t)T * 64;
  unsigned short* ld = ldbase + (H * 128 + wid * 8) * 64;
  gload16(gs, ld);
  gload16(gs + (size_t)64 * K, ld + 4096);
}

__device__ __forceinline__ void tile_step32(
    const unsigned short* __restrict__ sA, const unsigned short* __restrict__ sB,
    unsigned short* __restrict__ sAn,                                   // A1(t+1) dest (other buf)
    unsigned short* __restrict__ sAc, unsigned short* __restrict__ sBc, // t+2 dests (cur buf)
    int t1, int t2,
    const unsigned short* __restrict__ Ag, const unsigned short* __restrict__ Bg,
    size_t thrOff, int m0, int n0, int K, int wid,
    const int (&oA)[4][4], const int (&oB)[2][4], f32x16 (&acc)[4][2]) {
  short8 a[4][4], b[2][4];

  // reads group 1: b0 (4) + a01 (8); then stage A1(t+1)
#pragma unroll
  for (int ks = 0; ks < 4; ks++) b[0][ks] = *(const short8*)&sB[oB[0][ks]];
#pragma unroll
  for (int mt = 0; mt < 2; mt++)
#pragma unroll
    for (int ks = 0; ks < 4; ks++) a[mt][ks] = *(const short8*)&sA[oA[mt][ks]];
  stage_half(Ag, thrOff, K, m0, 1, t1, sAn, wid);
  SCH0;
  // reads group 2: b1 (4)
#pragma unroll
  for (int ks = 0; ks < 4; ks++) b[1][ks] = *(const short8*)&sB[oB[1][ks]];
  SCH0;
  // reads group 3: a23 (8)
#pragma unroll
  for (int mt = 2; mt < 4; mt++)
#pragma unroll
    for (int ks = 0; ks < 4; ks++) a[mt][ks] = *(const short8*)&sA[oA[mt][ks]];
  SCH0;
  PRIO1;   // c1: mt01 x jt0
#pragma unroll
  for (int ks = 0; ks < 4; ks++)
#pragma unroll
    for (int mt = 0; mt < 2; mt++)
      acc[mt][0] = MFMA32(a[mt][ks], b[0][ks], acc[mt][0]);
  PRIO0; SCH0;
  PRIO1;   // c2: mt01 x jt1
#pragma unroll
  for (int ks = 0; ks < 4; ks++)
#pragma unroll
    for (int mt = 0; mt < 2; mt++)
      acc[mt][1] = MFMA32(a[mt][ks], b[1][ks], acc[mt][1]);
  PRIO0; SCH0;
  PRIO1;   // c3: mt23 x jt0
#pragma unroll
  for (int ks = 0; ks < 4; ks++)
#pragma unroll
    for (int mt = 2; mt < 4; mt++)
      acc[mt][0] = MFMA32(a[mt][ks], b[0][ks], acc[mt][0]);
  PRIO0;
  SCH0; BARR; SCH0;   // BARR#1: every wave's 24 fragments are register-resident
  stage_half(Bg, thrOff, K, n0, 0, t2, sBc, wid);
  stage_half(Bg, thrOff, K, n0, 1, t2, sBc, wid);
  stage_half(Ag, thrOff, K, m0, 0, t2, sAc, wid);
  VMC6;               // drain all of tile t+1; (t+2).{B0,B1,A0} stay in flight
  SCH0; BARR; SCH0;   // BARR#2: publish t+1
  PRIO1;   // c4: mt23 x jt1 -- pure reg; next tile's reads stream underneath
#pragma unroll
  for (int ks = 0; ks < 4; ks++)
#pragma unroll
    for (int mt = 2; mt < 4; mt++)
      acc[mt][1] = MFMA32(a[mt][ks], b[1][ks], acc[mt][1]);
  PRIO0; SCH0;
}

__global__ __launch_bounds__(512) void gemm_dual8(
    const unsigned short* __restrict__ Xb, const unsigned short* __restrict__ Wx,
    const unsigned short* __restrict__ H0b, const unsigned short* __restrict__ Wh,
    const float* bx0, const float* bx1, const float* bx2, const float* bx3,
    const float* bh0, const float* bh1, const float* bh2, const float* bh3,
    unsigned short* __restrict__ Zx, unsigned short* __restrict__ Zh) {
  __shared__ __align__(16) unsigned short As[2][256 * 64];
  __shared__ __align__(16) unsigned short Bs[2][256 * 64];

  const unsigned short* Ag; const unsigned short* Bg;
  const float *p0, *p1, *p2, *p3; unsigned short* Cg; int K;
  if (blockIdx.z == 0) { Ag = Xb;  Bg = Wx; Cg = Zx; K = NIN; p0 = bx0; p1 = bx1; p2 = bx2; p3 = bx3; }
  else                 { Ag = H0b; Bg = Wh; Cg = Zh; K = NH;  p0 = bh0; p1 = bh1; p2 = bh2; p3 = bh3; }

  const int t    = threadIdx.x;
  const int wid  = t >> 6;
  const int lane = t & 63;
  const int r31  = lane & 31;
  const int hi   = lane >> 5;
  const int wm   = wid >> 2;     // 0..1 -> 128-row output band
  const int wn   = wid & 3;      // 0..3 -> 64-col output band
  const int rloc = lane >> 3;
  const int slot = lane & 7;
  const int ck   = slot ^ rloc ^ ((wid & 3) << 1);   // pre-swizzled global 16B chunk
  const int m0   = blockIdx.y * 256;
  const int n0   = blockIdx.x * 256;
  const int NT   = K >> 6;
  const size_t thrOff = (size_t)(wid * 8 + rloc) * K + ck * 8;

  // hoisted ds_read element offsets (loop-invariant); layouts from verified 32x32 kernel
  int oA[4][4], oB[2][4];
#pragma unroll
  for (int mt = 0; mt < 4; mt++) {
    const int row = wm * 128 + mt * 32 + r31;
#pragma unroll
    for (int ks = 0; ks < 4; ks++) oA[mt][ks] = row * 64 + (((ks * 2 + hi) ^ SWZ(row)) * 8);
  }
#pragma unroll
  for (int jt = 0; jt < 2; jt++) {
    const int row = wn * 64 + jt * 32 + r31;
#pragma unroll
    for (int ks = 0; ks < 4; ks++) oB[jt][ks] = row * 64 + (((ks * 2 + hi) ^ SWZ(row)) * 8);
  }

  f32x16 acc[4][2];
#pragma unroll
  for (int m = 0; m < 4; m++)
#pragma unroll
    for (int n = 0; n < 2; n++)
#pragma unroll
      for (int r = 0; r < 16; r++) acc[m][n][r] = 0.f;

  // prologue: tile0 all 4 halves + tile1 {B0,B1,A0}; A1(t1) staged in tile0 body
  stage_half(Ag, thrOff, K, m0, 0, 0, As[0], wid);
  stage_half(Ag, thrOff, K, m0, 1, 0, As[0], wid);
  stage_half(Bg, thrOff, K, n0, 0, 0, Bs[0], wid);
  stage_half(Bg, thrOff, K, n0, 1, 0, Bs[0], wid);
  stage_half(Bg, thrOff, K, n0, 0, 1, Bs[1], wid);
  stage_half(Bg, thrOff, K, n0, 1, 1, Bs[1], wid);
  stage_half(Ag, thrOff, K, m0, 0, 1, As[1], wid);
  VMC6;                      // 14 issued, wait 8 oldest -> tile0 landed
  SCH0; BARR; SCH0;

  for (int kt = 0; kt < NT; kt += 2) {
    const int t2a = (kt + 2 < NT) ? kt + 2 : NT - 1;
    const int t2b = (kt + 3 < NT) ? kt + 3 : NT - 1;
    tile_step32(As[0], Bs[0], As[1], As[0], Bs[0], kt + 1, t2a,
                Ag, Bg, thrOff, m0, n0, K, wid, oA, oB, acc);
    tile_step32(As[1], Bs[1], As[0], As[1], Bs[1], t2a, t2b,
                Ag, Bg, thrOff, m0, n0, K, wid, oA, oB, acc);
  }

  VMC0;                      // drain all LDS-DMA (incl. clamped tail stages)
  SCH0; BARR; SCH0;          // all waves drained -> As region safe to overwrite

  // ---------------- epilogue via LDS: full-line 128B global writes ----------------
  // Per-wave buffer: 32 rows x 68 shorts (8 waves x 4352B = 34816B, fits As).
  {
    unsigned short* wls = &As[0][0] + wid * (32 * 68);
    float bvn[2];
#pragma unroll
    for (int jt = 0; jt < 2; jt++) {
      const int col = n0 + wn * 64 + jt * 32 + r31;
      const float* bp = (col < 2048) ? p0 : ((col < 4096) ? p1 : ((col < 6144) ? p2 : p3));
      bvn[jt] = bp[col & 2047];
    }
    const int lrow0 = lane >> 3;
    const int lcol0 = (lane & 7) * 8;
#pragma unroll
    for (int mt = 0; mt < 4; mt++) {
#pragma unroll
      for (int jt = 0; jt < 2; jt++)
#pragma unroll
        for (int reg = 0; reg < 16; reg++) {
          const int lr = hi * 4 + (reg & 3) + 8 * (reg >> 2);
          wls[lr * 68 + jt * 32 + r31] = f2bf(acc[mt][jt][reg] + bvn[jt]);
        }
      LGKM0; SCH0;
#pragma unroll
      for (int i = 0; i < 4; i++) {
        const int lrow = i * 8 + lrow0;
        short8 v = *(const short8*)&wls[lrow * 68 + lcol0];
        *(short8*)&Cg[(size_t)(m0 + wm * 128 + mt * 32 + lrow) * NH4 + (n0 + wn * 64 + lcol0)] = v;
      }
      LGKM0; SCH0;   // reads done before next pass overwrites the buffer
    }
  }
}

// ---------------- NT GEMM core, 32x32x16 MFMA, BK=64 (kept for decoder) ----------------
template<int MT, bool BOUT>
__device__ __forceinline__ void gemm_core32(const unsigned short* __restrict__ A,
                                            const unsigned short* __restrict__ Bm,
                                            const float* b0p, const float* b1p,
                                            const float* b2p, const float* b3p,
                                            float* __restrict__ Cf, unsigned short* __restrict__ Cb,
                                            int N, int K) {
  constexpr int TM = MT * 64;
  __shared__ __align__(16) unsigned short As[TM * 64];
  __shared__ __align__(16) unsigned short Bs[128 * 64];
  const int t = threadIdx.x;
  const int w = t >> 6;
  const int lane = t & 63;
  const int r31 = lane & 31;
  const int hi = lane >> 5;
  const int rloc = lane >> 3;
  const int slot = lane & 7;
  const int m0 = blockIdx.y * TM;
  const int n0 = blockIdx.x * 128;
  const int wm = (w >> 1) * (MT * 32);
  const int wn = (w & 1) * 64;

  f32x16 acc[MT][2];
#pragma unroll
  for (int i = 0; i < MT; i++)
#pragma unroll
    for (int j = 0; j < 2; j++)
#pragma unroll
      for (int r = 0; r < 16; r++) acc[i][j][r] = 0.f;

  const unsigned short* AgP[2 * MT];
  unsigned short* AsP[2 * MT];
#pragma unroll
  for (int q = 0; q < 2 * MT; q++) {
    const int iss = w + 4 * q;
    const int bblk = slot ^ rloc ^ (iss & 3);
    AgP[q] = A + (size_t)(m0 + iss * 8 + rloc) * K + bblk * 8;
    AsP[q] = As + iss * 512;
  }
  const unsigned short* BgP[4];
  unsigned short* BsP[4];
#pragma unroll
  for (int q = 0; q < 4; q++) {
    const int iss = w + 4 * q;
    const int bblk = slot ^ rloc ^ (iss & 3);
    BgP[q] = Bm + (size_t)(n0 + iss * 8 + rloc) * K + bblk * 8;
    BsP[q] = Bs + iss * 512;
  }

  const int swz = (r31 & 7) ^ ((r31 >> 3) & 3);

  for (int k0 = 0; k0 < K; k0 += 64) {
#pragma unroll
    for (int q = 0; q < 2 * MT; q++) gload16(AgP[q] + k0, AsP[q]);
#pragma unroll
    for (int q = 0; q < 4; q++) gload16(BgP[q] + k0, BsP[q]);
    __syncthreads();

#pragma unroll
    for (int ks = 0; ks < 4; ks++) {
      const int phys = ((ks * 2 + hi) ^ swz) * 8;
      short8 af[MT], bf[2];
#pragma unroll
      for (int mt = 0; mt < MT; mt++) af[mt] = *(const short8*)&As[(wm + mt * 32 + r31) * 64 + phys];
#pragma unroll
      for (int jt = 0; jt < 2; jt++) bf[jt] = *(const short8*)&Bs[(wn + jt * 32 + r31) * 64 + phys];
#pragma unroll
      for (int mt = 0; mt < MT; mt++)
#pragma unroll
        for (int jt = 0; jt < 2; jt++)
          acc[mt][jt] = __builtin_amdgcn_mfma_f32_32x32x16_bf16(af[mt], bf[jt], acc[mt][jt], 0, 0, 0);
    }
    __syncthreads();
  }

#pragma unroll
  for (int mt = 0; mt < MT; mt++) {
#pragma unroll
    for (int jt = 0; jt < 2; jt++) {
      const int col = n0 + wn + jt * 32 + r31;
      const float* bp = (col < 2048) ? b0p : ((col < 4096) ? b1p : ((col < 6144) ? b2p : b3p));
      const float bv = bp[col & 2047];
      const int rowb = m0 + wm + mt * 32 + hi * 4;
#pragma unroll
      for (int reg = 0; reg < 16; reg++) {
        const int row = rowb + (reg & 3) + 8 * (reg >> 2);
        const float v = acc[mt][jt][reg] + bv;
        const size_t idx = (size_t)row * N + col;
        if (BOUT) Cb[idx] = f2bf(v);
        else      Cf[idx] = v;
      }
    }
  }
}

// decoder: 64x128 tile -> 512 blocks (2/CU)
__global__ __launch_bounds__(256) void gemm_dec(const unsigned short* __restrict__ HXb,
                                                const unsigned short* __restrict__ Wd,
                                                const float* __restrict__ bdec,
                                                float* __restrict__ out) {
  gemm_core32<1, false>(HXb, Wd, bdec, bdec, bdec, bdec, out, nullptr, NOUT, NH);
}

// ---------------- fused LN(zx)+LN(zh) -> gates -> cx -> LN(cx) -> hx ----------------
__global__ __launch_bounds__(256) void ln_gates(const unsigned short* __restrict__ Zx,
                                                const unsigned short* __restrict__ Zh,
                                                const float* __restrict__ c0,
                                                const float* __restrict__ ax, const float* __restrict__ bx,
                                                const float* __restrict__ ah, const float* __restrict__ bh,
                                                const float* __restrict__ ac, const float* __restrict__ bc,
                                                float* __restrict__ out_top,
                                                unsigned short* __restrict__ hx_bf) {
  const int b = blockIdx.x;
  const int t = threadIdx.x;
  const int n = t * 8;
  const int w = t >> 6;
  const int lane = t & 63;
  const float inv_n = 1.0f / 2048.0f, inv_nm1 = 1.0f / 2047.0f;

  short8 zx[4], zh[4];
  const size_t rowoff = (size_t)b * NH4;
#pragma unroll
  for (int g = 0; g < 4; g++) {
    zx[g] = *(const short8*)(Zx + rowoff + g * NH + n);
    zh[g] = *(const short8*)(Zh + rowoff + g * NH + n);
  }

  float s[16];
#pragma unroll
  for (int g = 0; g < 4; g++) {
    float su = 0, sq = 0, su2 = 0, sq2 = 0;
#pragma unroll
    for (int j = 0; j < 8; j++) {
      float v = bf2f((unsigned short)zx[g][j]); su += v; sq += v * v;
      float u = bf2f((unsigned short)zh[g][j]); su2 += u; sq2 += u * u;
    }
    s[g * 4 + 0] = su; s[g * 4 + 1] = sq; s[g * 4 + 2] = su2; s[g * 4 + 3] = sq2;
  }
#pragma unroll
  for (int i = 0; i < 16; i++) {
    float v = s[i];
#pragma unroll
    for (int o = 32; o > 0; o >>= 1) v += __shfl_xor(v, o, 64);
    s[i] = v;
  }
  __shared__ float red[4][16];
  __shared__ float red2[4][2];
  if (lane == 0) {
#pragma unroll
    for (int i = 0; i < 16; i++) red[w][i] = s[i];
  }
  __syncthreads();
#pragma unroll
  for (int i = 0; i < 16; i++) s[i] = red[0][i] + red[1][i] + red[2][i] + red[3][i];

  float mux[4], ivx[4], muh[4], ivh[4];
#pragma unroll
  for (int g = 0; g < 4; g++) {
    mux[g] = s[g * 4 + 0] * inv_n;
    float vx = fmaxf((s[g * 4 + 1] - s[g * 4 + 0] * mux[g]) * inv_nm1, 0.0f);
    ivx[g] = 1.0f / (sqrtf(vx) + 1e-5f);
    muh[g] = s[g * 4 + 2] * inv_n;
    float vh = fmaxf((s[g * 4 + 3] - s[g * 4 + 2] * muh[g]) * inv_nm1, 0.0f);
    ivh[g] = 1.0f / (sqrtf(vh) + 1e-5f);
  }

  float axl[8], bxl[8], ahl[8], bhl[8], c0l[8];
  *(float4*)&axl[0] = *(const float4*)(ax + n); *(float4*)&axl[4] = *(const float4*)(ax + n + 4);
  *(float4*)&bxl[0] = *(const float4*)(bx + n); *(float4*)&bxl[4] = *(const float4*)(bx + n + 4);
  *(float4*)&ahl[0] = *(const float4*)(ah + n); *(float4*)&ahl[4] = *(const float4*)(ah + n + 4);
  *(float4*)&bhl[0] = *(const float4*)(bh + n); *(float4*)&bhl[4] = *(const float4*)(bh + n + 4);
  const float* c0p = c0 + (size_t)b * NH + n;
  *(float4*)&c0l[0] = *(const float4*)(c0p); *(float4*)&c0l[4] = *(const float4*)(c0p + 4);

  float cx[8], og[8];
  float cs = 0, css = 0;
#pragma unroll
  for (int j = 0; j < 8; j++) {
    float pre[4];
#pragma unroll
    for (int g = 0; g < 4; g++) {
      float vx = bf2f((unsigned short)zx[g][j]);
      float vh = bf2f((unsigned short)zh[g][j]);
      pre[g] = ((vx - mux[g]) * ivx[g]) * axl[j] + bxl[j]
             + ((vh - muh[g]) * ivh[g]) * ahl[j] + bhl[j];
    }
    float fg = sigf(pre[0]);
    float ig = sigf(pre[1]);
    float ct = tanh_f(pre[2]);
    og[j] = sigf(pre[3]);
    float c = fg * c0l[j] + ig * ct;
    cx[j] = c; cs += c; css += c * c;
  }
#pragma unroll
  for (int o = 32; o > 0; o >>= 1) { cs += __shfl_xor(cs, o, 64); css += __shfl_xor(css, o, 64); }
  if (lane == 0) { red2[w][0] = cs; red2[w][1] = css; }
  __syncthreads();
  cs = red2[0][0] + red2[1][0] + red2[2][0] + red2[3][0];
  css = red2[0][1] + red2[1][1] + red2[2][1] + red2[3][1];
  const float muc = cs * inv_n;
  const float varc = fmaxf((css - cs * muc) * inv_nm1, 0.0f);
  const float ivc = 1.0f / (sqrtf(varc) + 1e-5f);

  float acl[8], bcl[8];
  *(float4*)&acl[0] = *(const float4*)(ac + n); *(float4*)&acl[4] = *(const float4*)(ac + n + 4);
  *(float4*)&bcl[0] = *(const float4*)(bc + n); *(float4*)&bcl[4] = *(const float4*)(bc + n + 4);

  float hx[8];
#pragma unroll
  for (int j = 0; j < 8; j++)
    hx[j] = og[j] * tanh_f((cx[j] - muc) * ivc * acl[j] + bcl[j]);

  // outputs: d_out = [out(B,OUT) | hx(B,H) | cx(B,H)]
  float* hx_out = out_top + (size_t)NB * NOUT + (size_t)b * NH + n;
  float* cx_out = out_top + (size_t)NB * NOUT + (size_t)NB * NH + (size_t)b * NH + n;
  float4 v;
  v.x = hx[0]; v.y = hx[1]; v.z = hx[2]; v.w = hx[3]; *(float4*)(hx_out) = v;
  v.x = hx[4]; v.y = hx[5]; v.z = hx[6]; v.w = hx[7]; *(float4*)(hx_out + 4) = v;
  v.x = cx[0]; v.y = cx[1]; v.z = cx[2]; v.w = cx[3]; *(float4*)(cx_out) = v;
  v.x = cx[4]; v.y = cx[5]; v.z = cx[6]; v.w = cx[7]; *(float4*)(cx_out + 4) = v;
  ushort8v hb;
#pragma unroll
  for (int j = 0; j < 8; j++) hb[j] = f2bf(hx[j]);
  *(ushort8v*)(hx_bf + (size_t)b * NH + n) = hb;
}

extern "C" void kernel_launch(void* const* d_in, const int* in_sizes, int n_in,
                              void* d_out, int out_size, void* d_ws, size_t ws_size,
                              hipStream_t stream) {
  const float* inp = (const float*)d_in[0];
  const float* h0  = (const float*)d_in[1];
  const float* c0  = (const float*)d_in[2];
  const float* bhg[4] = {(const float*)d_in[4], (const float*)d_in[6], (const float*)d_in[8], (const float*)d_in[10]};
  const float* bxg[4] = {(const float*)d_in[12], (const float*)d_in[14], (const float*)d_in[16], (const float*)d_in[18]};
  const float* bdec = (const float*)d_in[20];
  const float* ax = (const float*)d_in[21];
  const float* bx = (const float*)d_in[22];
  const float* ah = (const float*)d_in[23];
  const float* bh = (const float*)d_in[24];
  const float* ac = (const float*)d_in[25];
  const float* bc = (const float*)d_in[26];

  unsigned short* wsb = (unsigned short*)d_ws;
  unsigned short* Xb   = wsb + OFF_XB;
  unsigned short* H0b  = wsb + OFF_H0B;
  unsigned short* HXb  = wsb + OFF_HXB;
  unsigned short* Wx4b = wsb + OFF_WX;
  unsigned short* Wh4b = wsb + OFF_WH;
  unsigned short* Wdb  = wsb + OFF_WD;
  unsigned short* Zx   = wsb + OFF_ZX;
  unsigned short* Zh   = wsb + OFF_ZH;

  CvtArgs ca;
  ca.src[0] = inp; ca.src[1] = h0;
  ca.src[2] = (const float*)d_in[11]; ca.src[3] = (const float*)d_in[13];
  ca.src[4] = (const float*)d_in[15]; ca.src[5] = (const float*)d_in[17];
  ca.src[6] = (const float*)d_in[3];  ca.src[7] = (const float*)d_in[5];
  ca.src[8] = (const float*)d_in[7];  ca.src[9] = (const float*)d_in[9];
  ca.src[10] = (const float*)d_in[19];
  {
    const size_t nthr = CVT_TOTAL / 8;
    cvt_all<<<dim3((unsigned)((nthr + 255) / 256)), dim3(256), 0, stream>>>(ca, wsb);
  }

  gemm_dual8<<<dim3(NH4 / 256, NB / 256, 2), 512, 0, stream>>>(
      Xb, Wx4b, H0b, Wh4b,
      bxg[0], bxg[1], bxg[2], bxg[3],
      bhg[0], bhg[1], bhg[2], bhg[3],
      Zx, Zh);

  ln_gates<<<dim3(NB), 256, 0, stream>>>(Zx, Zh, c0, ax, bx, ah, bh, ac, bc, (float*)d_out, HXb);

  gemm_dec<<<dim3(NOUT / 128, NB / 64), 256, 0, stream>>>(HXb, Wdb, bdec, (float*)d_out);
}

// Round 6
// 555.738 us; speedup vs baseline: 1.0315x; 1.0315x over previous
//
#include <hip/hip_runtime.h>

#define NB   4096
#define NIN  1024
#define NH   2048
#define NOUT 1024
#define NH4  8192   // 4*NH

typedef short short8 __attribute__((ext_vector_type(8)));
typedef float f32x4 __attribute__((ext_vector_type(4)));
typedef float f32x16 __attribute__((ext_vector_type(16)));
typedef unsigned short ushort8v __attribute__((ext_vector_type(8)));

__device__ __forceinline__ float bf2f(unsigned short u) {
  union { unsigned int i; float f; } c; c.i = ((unsigned int)u) << 16; return c.f;
}
__device__ __forceinline__ unsigned short f2bf(float f) {
  union { float f; unsigned int i; } c; c.f = f;
  unsigned int u = c.i;
  u += 0x7FFFu + ((u >> 16) & 1u);   // RNE; inputs are finite
  return (unsigned short)(u >> 16);
}
__device__ __forceinline__ float sigf(float x) { return 1.0f / (1.0f + __expf(-x)); }
__device__ __forceinline__ float tanh_f(float x) { return 1.0f - 2.0f / (__expf(2.0f * x) + 1.0f); }

// ---------------- workspace layout (ushort elems), compile-time ----------------
#define CNT_INP  ((size_t)NB * NIN)
#define CNT_H0   ((size_t)NB * NH)
#define CNT_WXG  ((size_t)NH * NIN)
#define CNT_WHG  ((size_t)NH * NH)
#define CNT_WD   ((size_t)NOUT * NH)
#define OFF_XB   ((size_t)0)
#define OFF_H0B  (OFF_XB + CNT_INP)
#define OFF_HXB  (OFF_H0B + CNT_H0)
#define OFF_WX   (OFF_HXB + CNT_H0)
#define OFF_WH   (OFF_WX + 4 * CNT_WXG)
#define OFF_WD   (OFF_WH + 4 * CNT_WHG)
#define OFF_ZX   (OFF_WD + CNT_WD)
#define OFF_ZH   (OFF_ZX + (size_t)NB * NH4)
#define CVT_TOTAL (OFF_WD + CNT_WD)

// ---------------- single fused fp32->bf16 convert over all 11 segments ----------------
struct CvtArgs { const float* src[11]; };

__global__ __launch_bounds__(256) void cvt_all(CvtArgs a, unsigned short* __restrict__ dstBase) {
  const size_t i = ((size_t)blockIdx.x * 256 + threadIdx.x) * 8;
  if (i >= CVT_TOTAL) return;
  const size_t cnt[11] = {CNT_INP, CNT_H0, CNT_WXG, CNT_WXG, CNT_WXG, CNT_WXG,
                          CNT_WHG, CNT_WHG, CNT_WHG, CNT_WHG, CNT_WD};
  const size_t dst[11] = {OFF_XB, OFF_H0B,
                          OFF_WX, OFF_WX + CNT_WXG, OFF_WX + 2 * CNT_WXG, OFF_WX + 3 * CNT_WXG,
                          OFF_WH, OFF_WH + CNT_WHG, OFF_WH + 2 * CNT_WHG, OFF_WH + 3 * CNT_WHG,
                          OFF_WD};
  size_t base = 0;
#pragma unroll
  for (int s = 0; s < 11; s++) {
    if (i < base + cnt[s]) {
      const size_t off = i - base;
      const float* sp = a.src[s] + off;
      float4 v0 = *(const float4*)(sp);
      float4 v1 = *(const float4*)(sp + 4);
      ushort8v o;
      o[0] = f2bf(v0.x); o[1] = f2bf(v0.y); o[2] = f2bf(v0.z); o[3] = f2bf(v0.w);
      o[4] = f2bf(v1.x); o[5] = f2bf(v1.y); o[6] = f2bf(v1.z); o[7] = f2bf(v1.w);
      *(ushort8v*)(dstBase + dst[s] + off) = o;
      return;
    }
    base += cnt[s];
  }
}

// ---------------- async global->LDS, 16B/lane ----------------
__device__ __forceinline__ void gload16(const void* g, void* l) {
  __builtin_amdgcn_global_load_lds((const __attribute__((address_space(1))) void*)g,
                                   (__attribute__((address_space(3))) void*)l, 16, 0, 0);
}

#define SCH0  __builtin_amdgcn_sched_barrier(0)
#define BARR  __builtin_amdgcn_s_barrier()
#define LGKM0 asm volatile("s_waitcnt lgkmcnt(0)" ::: "memory")
#define VMC6  asm volatile("s_waitcnt vmcnt(6)" ::: "memory")
#define VMC0  asm volatile("s_waitcnt vmcnt(0)" ::: "memory")
#define PRIO1 __builtin_amdgcn_s_setprio(1)
#define PRIO0 __builtin_amdgcn_s_setprio(0)
#define MFMA32(A, B, C) __builtin_amdgcn_mfma_f32_32x32x16_bf16((A), (B), (C), 0, 0, 0)

// R5->R6: swizzle reverted to the OLD form — empirically 0-conflict for the
// 32-row read pattern (R0 counters + prior session's 932 TF kernel, identical
// read+stage pattern). The R3 "new" swizzle is 0-conflict ONLY for the 16-row
// paired pattern; with 32-row reads it measured 1.887e7 (R5) — the HW conflict
// rule distinguishes cases my lane-group models don't; trust measurement.
#define SWZ(R) (((R) & 7) ^ (((R) >> 3) & 3))

// ======================================================================
// 32x32x16 MFMA + early-publish 2-barrier rotation (R5 schedule, R0 swizzle).
// NT layout: C[m][n] = sum_k A[m,k]*B[n,k]. 512 thr = 8 waves (2M x 4N);
// per-wave 128x64; BK=64; LDS 128 KiB double-buffered.
//
// Per-tile schedule (clusters of 8 MFMA32):
//   reads b0(4)+a01(8); stage A1(t+1)->As[nxt]; reads b1(4); reads a23(8)
//   c1 (mt01 x jt0)  [counted lgkm: waits first 12 reads]
//   c2 (mt01 x jt1)  [16]
//   c3 (mt23 x jt0)  [24]
//   BARR#1; stage B0,B1(t+2)->Bs[cur], A0(t+2)->As[cur]; VMC6; BARR#2
//   c4 (mt23 x jt1)  [pure reg, overlaps next tile's 24 reads]
// vmcnt ledger: entry 6 (t+1.B0B1A0) +2(A1 t+1) +6(t+2) = 14; vmcnt(6)
// drains 8 oldest = all of t+1; BARR#2 publishes. Race proofs: staged regions'
// last readers moved data to regs before BARR#1 (A reads groups 1/3, B 1/2,
// all pre-BARR#1); A1(t+1)->other buf last read before t-1's BARR#1.
// Tail: clamped t1/t2 stages rewrite already-consumed regions (benign, counts
// exact); VMC0+BARR before epilogue reuses LDS.
//
// Swizzle: chunk c of row r at slot c^SWZ(r); staging pre-swizzles global
// chunk ck = slot^rloc^(wid&3) (staged rows have (row>>3)&3 == wid&3).
// Fragment/C layouts verbatim from the verified 32x32 kernel:
// A/B: m(n)=lane&31, k-chunk=ks*2+(lane>>5); C/D: col=lane&31,
// row=(reg&3)+8*(reg>>2)+4*(lane>>5).
// Epilogue (R2-verified WRITE_SIZE=ideal): per-wave 32x68 LDS buffer,
// readback b128, 128B fully-covered global segments.
// ======================================================================

__device__ __forceinline__ void stage_half(const unsigned short* __restrict__ G, size_t thrOff, int K,
                                           int R0, int H, int T, unsigned short* __restrict__ ldbase, int wid) {
  const unsigned short* gs = G + thrOff + (size_t)(R0 + H * 128) * K + (size_t)T * 64;
  unsigned short* ld = ldbase + (H * 128 + wid * 8) * 64;
  gload16(gs, ld);
  gload16(gs + (size_t)64 * K, ld + 4096);
}

__device__ __forceinline__ void tile_step32(
    const unsigned short* __restrict__ sA, const unsigned short* __restrict__ sB,
    unsigned short* __restrict__ sAn,                                   // A1(t+1) dest (other buf)
    unsigned short* __restrict__ sAc, unsigned short* __restrict__ sBc, // t+2 dests (cur buf)
    int t1, int t2,
    const unsigned short* __restrict__ Ag, const unsigned short* __restrict__ Bg,
    size_t thrOff, int m0, int n0, int K, int wid,
    const int (&oA)[4][4], const int (&oB)[2][4], f32x16 (&acc)[4][2]) {
  short8 a[4][4], b[2][4];

  // reads group 1: b0 (4) + a01 (8); then stage A1(t+1)
#pragma unroll
  for (int ks = 0; ks < 4; ks++) b[0][ks] = *(const short8*)&sB[oB[0][ks]];
#pragma unroll
  for (int mt = 0; mt < 2; mt++)
#pragma unroll
    for (int ks = 0; ks < 4; ks++) a[mt][ks] = *(const short8*)&sA[oA[mt][ks]];
  stage_half(Ag, thrOff, K, m0, 1, t1, sAn, wid);
  SCH0;
  // reads group 2: b1 (4)
#pragma unroll
  for (int ks = 0; ks < 4; ks++) b[1][ks] = *(const short8*)&sB[oB[1][ks]];
  SCH0;
  // reads group 3: a23 (8)
#pragma unroll
  for (int mt = 2; mt < 4; mt++)
#pragma unroll
    for (int ks = 0; ks < 4; ks++) a[mt][ks] = *(const short8*)&sA[oA[mt][ks]];
  SCH0;
  PRIO1;   // c1: mt01 x jt0
#pragma unroll
  for (int ks = 0; ks < 4; ks++)
#pragma unroll
    for (int mt = 0; mt < 2; mt++)
      acc[mt][0] = MFMA32(a[mt][ks], b[0][ks], acc[mt][0]);
  PRIO0; SCH0;
  PRIO1;   // c2: mt01 x jt1
#pragma unroll
  for (int ks = 0; ks < 4; ks++)
#pragma unroll
    for (int mt = 0; mt < 2; mt++)
      acc[mt][1] = MFMA32(a[mt][ks], b[1][ks], acc[mt][1]);
  PRIO0; SCH0;
  PRIO1;   // c3: mt23 x jt0
#pragma unroll
  for (int ks = 0; ks < 4; ks++)
#pragma unroll
    for (int mt = 2; mt < 4; mt++)
      acc[mt][0] = MFMA32(a[mt][ks], b[0][ks], acc[mt][0]);
  PRIO0;
  SCH0; BARR; SCH0;   // BARR#1: every wave's 24 fragments are register-resident
  stage_half(Bg, thrOff, K, n0, 0, t2, sBc, wid);
  stage_half(Bg, thrOff, K, n0, 1, t2, sBc, wid);
  stage_half(Ag, thrOff, K, m0, 0, t2, sAc, wid);
  VMC6;               // drain all of tile t+1; (t+2).{B0,B1,A0} stay in flight
  SCH0; BARR; SCH0;   // BARR#2: publish t+1
  PRIO1;   // c4: mt23 x jt1 -- pure reg; next tile's reads stream underneath
#pragma unroll
  for (int ks = 0; ks < 4; ks++)
#pragma unroll
    for (int mt = 2; mt < 4; mt++)
      acc[mt][1] = MFMA32(a[mt][ks], b[1][ks], acc[mt][1]);
  PRIO0; SCH0;
}

__global__ __launch_bounds__(512) void gemm_dual8(
    const unsigned short* __restrict__ Xb, const unsigned short* __restrict__ Wx,
    const unsigned short* __restrict__ H0b, const unsigned short* __restrict__ Wh,
    const float* bx0, const float* bx1, const float* bx2, const float* bx3,
    const float* bh0, const float* bh1, const float* bh2, const float* bh3,
    unsigned short* __restrict__ Zx, unsigned short* __restrict__ Zh) {
  __shared__ __align__(16) unsigned short As[2][256 * 64];
  __shared__ __align__(16) unsigned short Bs[2][256 * 64];

  const unsigned short* Ag; const unsigned short* Bg;
  const float *p0, *p1, *p2, *p3; unsigned short* Cg; int K;
  if (blockIdx.z == 0) { Ag = Xb;  Bg = Wx; Cg = Zx; K = NIN; p0 = bx0; p1 = bx1; p2 = bx2; p3 = bx3; }
  else                 { Ag = H0b; Bg = Wh; Cg = Zh; K = NH;  p0 = bh0; p1 = bh1; p2 = bh2; p3 = bh3; }

  const int t    = threadIdx.x;
  const int wid  = t >> 6;
  const int lane = t & 63;
  const int r31  = lane & 31;
  const int hi   = lane >> 5;
  const int wm   = wid >> 2;     // 0..1 -> 128-row output band
  const int wn   = wid & 3;      // 0..3 -> 64-col output band
  const int rloc = lane >> 3;
  const int slot = lane & 7;
  const int ck   = slot ^ rloc ^ (wid & 3);   // pre-swizzled global 16B chunk (old swz)
  const int m0   = blockIdx.y * 256;
  const int n0   = blockIdx.x * 256;
  const int NT   = K >> 6;
  const size_t thrOff = (size_t)(wid * 8 + rloc) * K + ck * 8;

  // hoisted ds_read element offsets (loop-invariant); layouts from verified 32x32 kernel
  int oA[4][4], oB[2][4];
#pragma unroll
  for (int mt = 0; mt < 4; mt++) {
    const int row = wm * 128 + mt * 32 + r31;
#pragma unroll
    for (int ks = 0; ks < 4; ks++) oA[mt][ks] = row * 64 + (((ks * 2 + hi) ^ SWZ(row)) * 8);
  }
#pragma unroll
  for (int jt = 0; jt < 2; jt++) {
    const int row = wn * 64 + jt * 32 + r31;
#pragma unroll
    for (int ks = 0; ks < 4; ks++) oB[jt][ks] = row * 64 + (((ks * 2 + hi) ^ SWZ(row)) * 8);
  }

  f32x16 acc[4][2];
#pragma unroll
  for (int m = 0; m < 4; m++)
#pragma unroll
    for (int n = 0; n < 2; n++)
#pragma unroll
      for (int r = 0; r < 16; r++) acc[m][n][r] = 0.f;

  // prologue: tile0 all 4 halves + tile1 {B0,B1,A0}; A1(t1) staged in tile0 body
  stage_half(Ag, thrOff, K, m0, 0, 0, As[0], wid);
  stage_half(Ag, thrOff, K, m0, 1, 0, As[0], wid);
  stage_half(Bg, thrOff, K, n0, 0, 0, Bs[0], wid);
  stage_half(Bg, thrOff, K, n0, 1, 0, Bs[0], wid);
  stage_half(Bg, thrOff, K, n0, 0, 1, Bs[1], wid);
  stage_half(Bg, thrOff, K, n0, 1, 1, Bs[1], wid);
  stage_half(Ag, thrOff, K, m0, 0, 1, As[1], wid);
  VMC6;                      // 14 issued, wait 8 oldest -> tile0 landed
  SCH0; BARR; SCH0;

  for (int kt = 0; kt < NT; kt += 2) {
    const int t2a = (kt + 2 < NT) ? kt + 2 : NT - 1;
    const int t2b = (kt + 3 < NT) ? kt + 3 : NT - 1;
    tile_step32(As[0], Bs[0], As[1], As[0], Bs[0], kt + 1, t2a,
                Ag, Bg, thrOff, m0, n0, K, wid, oA, oB, acc);
    tile_step32(As[1], Bs[1], As[0], As[1], Bs[1], t2a, t2b,
                Ag, Bg, thrOff, m0, n0, K, wid, oA, oB, acc);
  }

  VMC0;                      // drain all LDS-DMA (incl. clamped tail stages)
  SCH0; BARR; SCH0;          // all waves drained -> As region safe to overwrite

  // ---------------- epilogue via LDS: full-line 128B global writes ----------------
  // Per-wave buffer: 32 rows x 68 shorts (8 waves x 4352B = 34816B, fits As).
  {
    unsigned short* wls = &As[0][0] + wid * (32 * 68);
    float bvn[2];
#pragma unroll
    for (int jt = 0; jt < 2; jt++) {
      const int col = n0 + wn * 64 + jt * 32 + r31;
      const float* bp = (col < 2048) ? p0 : ((col < 4096) ? p1 : ((col < 6144) ? p2 : p3));
      bvn[jt] = bp[col & 2047];
    }
    const int lrow0 = lane >> 3;
    const int lcol0 = (lane & 7) * 8;
#pragma unroll
    for (int mt = 0; mt < 4; mt++) {
#pragma unroll
      for (int jt = 0; jt < 2; jt++)
#pragma unroll
        for (int reg = 0; reg < 16; reg++) {
          const int lr = hi * 4 + (reg & 3) + 8 * (reg >> 2);
          wls[lr * 68 + jt * 32 + r31] = f2bf(acc[mt][jt][reg] + bvn[jt]);
        }
      LGKM0; SCH0;
#pragma unroll
      for (int i = 0; i < 4; i++) {
        const int lrow = i * 8 + lrow0;
        short8 v = *(const short8*)&wls[lrow * 68 + lcol0];
        *(short8*)&Cg[(size_t)(m0 + wm * 128 + mt * 32 + lrow) * NH4 + (n0 + wn * 64 + lcol0)] = v;
      }
      LGKM0; SCH0;   // reads done before next pass overwrites the buffer
    }
  }
}

// ---------------- NT GEMM core, 32x32x16 MFMA, BK=64 (kept for decoder) ----------------
template<int MT, bool BOUT>
__device__ __forceinline__ void gemm_core32(const unsigned short* __restrict__ A,
                                            const unsigned short* __restrict__ Bm,
                                            const float* b0p, const float* b1p,
                                            const float* b2p, const float* b3p,
                                            float* __restrict__ Cf, unsigned short* __restrict__ Cb,
                                            int N, int K) {
  constexpr int TM = MT * 64;
  __shared__ __align__(16) unsigned short As[TM * 64];
  __shared__ __align__(16) unsigned short Bs[128 * 64];
  const int t = threadIdx.x;
  const int w = t >> 6;
  const int lane = t & 63;
  const int r31 = lane & 31;
  const int hi = lane >> 5;
  const int rloc = lane >> 3;
  const int slot = lane & 7;
  const int m0 = blockIdx.y * TM;
  const int n0 = blockIdx.x * 128;
  const int wm = (w >> 1) * (MT * 32);
  const int wn = (w & 1) * 64;

  f32x16 acc[MT][2];
#pragma unroll
  for (int i = 0; i < MT; i++)
#pragma unroll
    for (int j = 0; j < 2; j++)
#pragma unroll
      for (int r = 0; r < 16; r++) acc[i][j][r] = 0.f;

  const unsigned short* AgP[2 * MT];
  unsigned short* AsP[2 * MT];
#pragma unroll
  for (int q = 0; q < 2 * MT; q++) {
    const int iss = w + 4 * q;
    const int bblk = slot ^ rloc ^ (iss & 3);
    AgP[q] = A + (size_t)(m0 + iss * 8 + rloc) * K + bblk * 8;
    AsP[q] = As + iss * 512;
  }
  const unsigned short* BgP[4];
  unsigned short* BsP[4];
#pragma unroll
  for (int q = 0; q < 4; q++) {
    const int iss = w + 4 * q;
    const int bblk = slot ^ rloc ^ (iss & 3);
    BgP[q] = Bm + (size_t)(n0 + iss * 8 + rloc) * K + bblk * 8;
    BsP[q] = Bs + iss * 512;
  }

  const int swz = (r31 & 7) ^ ((r31 >> 3) & 3);

  for (int k0 = 0; k0 < K; k0 += 64) {
#pragma unroll
    for (int q = 0; q < 2 * MT; q++) gload16(AgP[q] + k0, AsP[q]);
#pragma unroll
    for (int q = 0; q < 4; q++) gload16(BgP[q] + k0, BsP[q]);
    __syncthreads();

#pragma unroll
    for (int ks = 0; ks < 4; ks++) {
      const int phys = ((ks * 2 + hi) ^ swz) * 8;
      short8 af[MT], bf[2];
#pragma unroll
      for (int mt = 0; mt < MT; mt++) af[mt] = *(const short8*)&As[(wm + mt * 32 + r31) * 64 + phys];
#pragma unroll
      for (int jt = 0; jt < 2; jt++) bf[jt] = *(const short8*)&Bs[(wn + jt * 32 + r31) * 64 + phys];
#pragma unroll
      for (int mt = 0; mt < MT; mt++)
#pragma unroll
        for (int jt = 0; jt < 2; jt++)
          acc[mt][jt] = __builtin_amdgcn_mfma_f32_32x32x16_bf16(af[mt], bf[jt], acc[mt][jt], 0, 0, 0);
    }
    __syncthreads();
  }

#pragma unroll
  for (int mt = 0; mt < MT; mt++) {
#pragma unroll
    for (int jt = 0; jt < 2; jt++) {
      const int col = n0 + wn + jt * 32 + r31;
      const float* bp = (col < 2048) ? b0p : ((col < 4096) ? b1p : ((col < 6144) ? b2p : b3p));
      const float bv = bp[col & 2047];
      const int rowb = m0 + wm + mt * 32 + hi * 4;
#pragma unroll
      for (int reg = 0; reg < 16; reg++) {
        const int row = rowb + (reg & 3) + 8 * (reg >> 2);
        const float v = acc[mt][jt][reg] + bv;
        const size_t idx = (size_t)row * N + col;
        if (BOUT) Cb[idx] = f2bf(v);
        else      Cf[idx] = v;
      }
    }
  }
}

// decoder: 64x128 tile -> 512 blocks (2/CU)
__global__ __launch_bounds__(256) void gemm_dec(const unsigned short* __restrict__ HXb,
                                                const unsigned short* __restrict__ Wd,
                                                const float* __restrict__ bdec,
                                                float* __restrict__ out) {
  gemm_core32<1, false>(HXb, Wd, bdec, bdec, bdec, bdec, out, nullptr, NOUT, NH);
}

// ---------------- fused LN(zx)+LN(zh) -> gates -> cx -> LN(cx) -> hx ----------------
__global__ __launch_bounds__(256) void ln_gates(const unsigned short* __restrict__ Zx,
                                                const unsigned short* __restrict__ Zh,
                                                const float* __restrict__ c0,
                                                const float* __restrict__ ax, const float* __restrict__ bx,
                                                const float* __restrict__ ah, const float* __restrict__ bh,
                                                const float* __restrict__ ac, const float* __restrict__ bc,
                                                float* __restrict__ out_top,
                                                unsigned short* __restrict__ hx_bf) {
  const int b = blockIdx.x;
  const int t = threadIdx.x;
  const int n = t * 8;
  const int w = t >> 6;
  const int lane = t & 63;
  const float inv_n = 1.0f / 2048.0f, inv_nm1 = 1.0f / 2047.0f;

  short8 zx[4], zh[4];
  const size_t rowoff = (size_t)b * NH4;
#pragma unroll
  for (int g = 0; g < 4; g++) {
    zx[g] = *(const short8*)(Zx + rowoff + g * NH + n);
    zh[g] = *(const short8*)(Zh + rowoff + g * NH + n);
  }

  float s[16];
#pragma unroll
  for (int g = 0; g < 4; g++) {
    float su = 0, sq = 0, su2 = 0, sq2 = 0;
#pragma unroll
    for (int j = 0; j < 8; j++) {
      float v = bf2f((unsigned short)zx[g][j]); su += v; sq += v * v;
      float u = bf2f((unsigned short)zh[g][j]); su2 += u; sq2 += u * u;
    }
    s[g * 4 + 0] = su; s[g * 4 + 1] = sq; s[g * 4 + 2] = su2; s[g * 4 + 3] = sq2;
  }
#pragma unroll
  for (int i = 0; i < 16; i++) {
    float v = s[i];
#pragma unroll
    for (int o = 32; o > 0; o >>= 1) v += __shfl_xor(v, o, 64);
    s[i] = v;
  }
  __shared__ float red[4][16];
  __shared__ float red2[4][2];
  if (lane == 0) {
#pragma unroll
    for (int i = 0; i < 16; i++) red[w][i] = s[i];
  }
  __syncthreads();
#pragma unroll
  for (int i = 0; i < 16; i++) s[i] = red[0][i] + red[1][i] + red[2][i] + red[3][i];

  float mux[4], ivx[4], muh[4], ivh[4];
#pragma unroll
  for (int g = 0; g < 4; g++) {
    mux[g] = s[g * 4 + 0] * inv_n;
    float vx = fmaxf((s[g * 4 + 1] - s[g * 4 + 0] * mux[g]) * inv_nm1, 0.0f);
    ivx[g] = 1.0f / (sqrtf(vx) + 1e-5f);
    muh[g] = s[g * 4 + 2] * inv_n;
    float vh = fmaxf((s[g * 4 + 3] - s[g * 4 + 2] * muh[g]) * inv_nm1, 0.0f);
    ivh[g] = 1.0f / (sqrtf(vh) + 1e-5f);
  }

  float axl[8], bxl[8], ahl[8], bhl[8], c0l[8];
  *(float4*)&axl[0] = *(const float4*)(ax + n); *(float4*)&axl[4] = *(const float4*)(ax + n + 4);
  *(float4*)&bxl[0] = *(const float4*)(bx + n); *(float4*)&bxl[4] = *(const float4*)(bx + n + 4);
  *(float4*)&ahl[0] = *(const float4*)(ah + n); *(float4*)&ahl[4] = *(const float4*)(ah + n + 4);
  *(float4*)&bhl[0] = *(const float4*)(bh + n); *(float4*)&bhl[4] = *(const float4*)(bh + n + 4);
  const float* c0p = c0 + (size_t)b * NH + n;
  *(float4*)&c0l[0] = *(const float4*)(c0p); *(float4*)&c0l[4] = *(const float4*)(c0p + 4);

  float cx[8], og[8];
  float cs = 0, css = 0;
#pragma unroll
  for (int j = 0; j < 8; j++) {
    float pre[4];
#pragma unroll
    for (int g = 0; g < 4; g++) {
      float vx = bf2f((unsigned short)zx[g][j]);
      float vh = bf2f((unsigned short)zh[g][j]);
      pre[g] = ((vx - mux[g]) * ivx[g]) * axl[j] + bxl[j]
             + ((vh - muh[g]) * ivh[g]) * ahl[j] + bhl[j];
    }
    float fg = sigf(pre[0]);
    float ig = sigf(pre[1]);
    float ct = tanh_f(pre[2]);
    og[j] = sigf(pre[3]);
    float c = fg * c0l[j] + ig * ct;
    cx[j] = c; cs += c; css += c * c;
  }
#pragma unroll
  for (int o = 32; o > 0; o >>= 1) { cs += __shfl_xor(cs, o, 64); css += __shfl_xor(css, o, 64); }
  if (lane == 0) { red2[w][0] = cs; red2[w][1] = css; }
  __syncthreads();
  cs = red2[0][0] + red2[1][0] + red2[2][0] + red2[3][0];
  css = red2[0][1] + red2[1][1] + red2[2][1] + red2[3][1];
  const float muc = cs * inv_n;
  const float varc = fmaxf((css - cs * muc) * inv_nm1, 0.0f);
  const float ivc = 1.0f / (sqrtf(varc) + 1e-5f);

  float acl[8], bcl[8];
  *(float4*)&acl[0] = *(const float4*)(ac + n); *(float4*)&acl[4] = *(const float4*)(ac + n + 4);
  *(float4*)&bcl[0] = *(const float4*)(bc + n); *(float4*)&bcl[4] = *(const float4*)(bc + n + 4);

  float hx[8];
#pragma unroll
  for (int j = 0; j < 8; j++)
    hx[j] = og[j] * tanh_f((cx[j] - muc) * ivc * acl[j] + bcl[j]);

  // outputs: d_out = [out(B,OUT) | hx(B,H) | cx(B,H)]
  float* hx_out = out_top + (size_t)NB * NOUT + (size_t)b * NH + n;
  float* cx_out = out_top + (size_t)NB * NOUT + (size_t)NB * NH + (size_t)b * NH + n;
  float4 v;
  v.x = hx[0]; v.y = hx[1]; v.z = hx[2]; v.w = hx[3]; *(float4*)(hx_out) = v;
  v.x = hx[4]; v.y = hx[5]; v.z = hx[6]; v.w = hx[7]; *(float4*)(hx_out + 4) = v;
  v.x = cx[0]; v.y = cx[1]; v.z = cx[2]; v.w = cx[3]; *(float4*)(cx_out) = v;
  v.x = cx[4]; v.y = cx[5]; v.z = cx[6]; v.w = cx[7]; *(float4*)(cx_out + 4) = v;
  ushort8v hb;
#pragma unroll
  for (int j = 0; j < 8; j++) hb[j] = f2bf(hx[j]);
  *(ushort8v*)(hx_bf + (size_t)b * NH + n) = hb;
}

extern "C" void kernel_launch(void* const* d_in, const int* in_sizes, int n_in,
                              void* d_out, int out_size, void* d_ws, size_t ws_size,
                              hipStream_t stream) {
  const float* inp = (const float*)d_in[0];
  const float* h0  = (const float*)d_in[1];
  const float* c0  = (const float*)d_in[2];
  const float* bhg[4] = {(const float*)d_in[4], (const float*)d_in[6], (const float*)d_in[8], (const float*)d_in[10]};
  const float* bxg[4] = {(const float*)d_in[12], (const float*)d_in[14], (const float*)d_in[16], (const float*)d_in[18]};
  const float* bdec = (const float*)d_in[20];
  const float* ax = (const float*)d_in[21];
  const float* bx = (const float*)d_in[22];
  const float* ah = (const float*)d_in[23];
  const float* bh = (const float*)d_in[24];
  const float* ac = (const float*)d_in[25];
  const float* bc = (const float*)d_in[26];

  unsigned short* wsb = (unsigned short*)d_ws;
  unsigned short* Xb   = wsb + OFF_XB;
  unsigned short* H0b  = wsb + OFF_H0B;
  unsigned short* HXb  = wsb + OFF_HXB;
  unsigned short* Wx4b = wsb + OFF_WX;
  unsigned short* Wh4b = wsb + OFF_WH;
  unsigned short* Wdb  = wsb + OFF_WD;
  unsigned short* Zx   = wsb + OFF_ZX;
  unsigned short* Zh   = wsb + OFF_ZH;

  CvtArgs ca;
  ca.src[0] = inp; ca.src[1] = h0;
  ca.src[2] = (const float*)d_in[11]; ca.src[3] = (const float*)d_in[13];
  ca.src[4] = (const float*)d_in[15]; ca.src[5] = (const float*)d_in[17];
  ca.src[6] = (const float*)d_in[3];  ca.src[7] = (const float*)d_in[5];
  ca.src[8] = (const float*)d_in[7];  ca.src[9] = (const float*)d_in[9];
  ca.src[10] = (const float*)d_in[19];
  {
    const size_t nthr = CVT_TOTAL / 8;
    cvt_all<<<dim3((unsigned)((nthr + 255) / 256)), dim3(256), 0, stream>>>(ca, wsb);
  }

  gemm_dual8<<<dim3(NH4 / 256, NB / 256, 2), 512, 0, stream>>>(
      Xb, Wx4b, H0b, Wh4b,
      bxg[0], bxg[1], bxg[2], bxg[3],
      bhg[0], bhg[1], bhg[2], bhg[3],
      Zx, Zh);

  ln_gates<<<dim3(NB), 256, 0, stream>>>(Zx, Zh, c0, ax, bx, ah, bh, ac, bc, (float*)d_out, HXb);

  gemm_dec<<<dim3(NOUT / 128, NB / 64), 256, 0, stream>>>(HXb, Wdb, bdec, (float*)d_out);
}